// Round 9
// baseline (122.431 us; speedup 1.0000x reference)
//
#include <hip/hip_runtime.h>
#include <hip/hip_bf16.h>

typedef unsigned short u16;
typedef __attribute__((ext_vector_type(8))) short short8;
typedef __attribute__((ext_vector_type(4))) float floatx4;

#define NROWS 8192
#define DIM 256
#define BM 128        // rows per block
#define NCT 4         // col-tiles (128 cols each) per block -> 512 cols
#define NKB 8         // 32-wide k-chunks per row (A LDS layout)
#define BK 32

__device__ __forceinline__ void atomicMinFloat(float* addr, float val) {
    if (val >= 0.0f) {
        atomicMin((int*)addr, __float_as_int(val));
    } else {
        atomicMax((unsigned int*)addr, __float_as_uint(val));
    }
}

__device__ __forceinline__ u16 f32_to_bf16_rne(float x) {
    unsigned int u = __float_as_uint(x);
    unsigned int r = (u + 0x7fffu + ((u >> 16) & 1u)) >> 16;
    return (u16)r;
}

// C(M) = -logp * exp(logp); quasiconcave in M => rowmin = min(C(minM), C(maxM)).
__device__ __forceinline__ float c_of_m(float m) {
    const float INV_SIG = 1.0f / 0.3f;
    const float KC = 0.28503427f;  // -ln(0.3) - 0.5*ln(2*pi)
    float z = (m - 1.0f) * INV_SIG;
    float logp = fmaf(-0.5f * z, z, KC);
    return -logp * __expf(logp);
}

// 16B async DMA global -> LDS. LDS dest is wave-uniform base + lane*16.
__device__ __forceinline__ void load16(const u16* g, u16* l) {
    __builtin_amdgcn_global_load_lds(
        (__attribute__((address_space(1))) void*)g,
        (__attribute__((address_space(3))) void*)l, 16, 0, 0);
}

// Normalize rows (L2-norm clamped at 1e-8), wave per row, float4 loads.
// blockIdx.y==0: X -> row-major Xn (GEMM stages it to LDS) + out[] init.
// blockIdx.y==1: Y -> MFMA B-panel layout Ys: element (row r, k) at
//   ((p*8+kt)*64 + lq*16 + lm)*8 + j  (p=r>>4, lm=r&15, kt=k>>5,
//   lq=(k>>3)&3, j=k&7). B-fragment load = base + lane*16B, one dwordx4.
// (Layout + GEMM consumption correctness-verified R7/R8: absmax 1.5e-5.)
__global__ __launch_bounds__(256) void normalize_kernel(const float* __restrict__ Ex,
                                                        const float* __restrict__ Ey,
                                                        u16* __restrict__ Xn,
                                                        u16* __restrict__ Ys,
                                                        float* __restrict__ out) {
    const int t = threadIdx.x;
    const int ln = t & 63;
    const int row = blockIdx.x * 4 + (t >> 6);
    const float* src = (blockIdx.y == 0) ? Ex : Ey;

    float4 v = *(const float4*)(src + (size_t)row * DIM + ln * 4);
    float s = fmaf(v.x, v.x, fmaf(v.y, v.y, fmaf(v.z, v.z, v.w * v.w)));
    #pragma unroll
    for (int m = 32; m >= 1; m >>= 1) s += __shfl_xor(s, m, 64);
    float inv = 1.0f / fmaxf(sqrtf(s), 1e-8f);

    ushort4 o;
    o.x = f32_to_bf16_rne(v.x * inv);
    o.y = f32_to_bf16_rne(v.y * inv);
    o.z = f32_to_bf16_rne(v.z * inv);
    o.w = f32_to_bf16_rne(v.w * inv);

    if (blockIdx.y == 0) {
        *(ushort4*)(Xn + (size_t)row * DIM + ln * 4) = o;
        if (ln == 0) out[row] = __uint_as_float(0x7f800000u);  // +inf
    } else {
        const int p = row >> 4;
        const int lm = row & 15;
        const int kt = ln >> 3;
        const int lq = (ln >> 1) & 3;
        const int j4 = (ln & 1) * 4;
        const size_t off = ((size_t)((p * NKB + kt) * 64 + lq * 16 + lm)) * 8 + j4;
        *(ushort4*)(Ys + off) = o;
    }
}

// Load one BK=64 body's 8 B-fragments (4 panels x 2 k-chunks) into a named
// register buffer. Panel stride 4096 els, k-chunk stride 512 els.
#define LOADB64(dst, base, j)                                                          \
    {                                                                                  \
        _Pragma("unroll")                                                              \
        for (int cg = 0; cg < 4; ++cg) {                                               \
            dst[cg * 2 + 0] = *(const short8*)((base) + cg * 4096 + ((j) * 2 + 0) * 512); \
            dst[cg * 2 + 1] = *(const short8*)((base) + cg * 4096 + ((j) * 2 + 1) * 512); \
        }                                                                              \
    }

// One BK=64 body: 2 k-halves x (4 A-frag ds_reads + 16 MFMAs) = 32 MFMAs
// (~620 cyc of matrix-pipe issue) consuming buffer `buf`.
#define BODY(buf, j)                                                                   \
    {                                                                                  \
        _Pragma("unroll")                                                              \
        for (int h = 0; h < 2; ++h) {                                                  \
            short8 a[4];                                                               \
            _Pragma("unroll")                                                          \
            for (int rg = 0; rg < 4; ++rg)                                             \
                a[rg] = *(const short8*)(&As[(j) * 2 + h][aoff[rg]]);                  \
            _Pragma("unroll")                                                          \
            for (int rg = 0; rg < 4; ++rg)                                             \
                _Pragma("unroll")                                                      \
                for (int cg = 0; cg < 4; ++cg)                                         \
                    acc[rg][cg] = __builtin_amdgcn_mfma_f32_16x16x32_bf16(             \
                        a[rg], buf[cg * 2 + h], acc[rg][cg], 0, 0, 0);                 \
        }                                                                              \
    }

// Block = 128 rows x 512 cols. A (128x256, 64 KB) staged to LDS ONCE
// (xor-swizzled, conflict-free b128 reads), ONE barrier. K-stream = 16
// bodies of BK=64 with ZERO barriers: A from LDS, B direct from the
// panel-layout Ys (L2-resident strip) via a P/Q register double-buffer
// with ONE-BODY prefetch distance -- 32 MFMAs (~620 cyc) per body exceeds
// L2 latency, so a 1-body distance suffices and only needs 2x32 VGPRs.
// amdgpu_waves_per_eu(2,2): occupancy is LDS-capped at 2 blocks/CU anyway;
// granting the full 256-reg budget stops the allocator from serializing
// loads into their consumers (R8's collapse: VGPR=128, prefetch dead).
// ct loop is unroll-1 with loop-carried ybase (anti-hoist fence, R7 lesson).
// Grid: b&63 = row-tile (fixed A set per XCD), b>>6 = colgroup.
__global__ void __launch_bounds__(256, 2) __attribute__((amdgpu_waves_per_eu(2, 2)))
gemm_min_kernel(const u16* __restrict__ Xn,
                const u16* __restrict__ Ys,
                float* __restrict__ out) {
    __shared__ u16 As[NKB][BM * BK];  // 64 KB, full-K A

    const int tid = threadIdx.x;
    const int w = tid >> 6;
    const int lane = tid & 63;
    const int wr = w >> 1;
    const int wc = w & 1;
    const int lq = lane >> 4;
    const int lm = lane & 15;
    const int swz = (lm >> 1) & 3;

    const int b = blockIdx.x;
    const int rowStart = (b & 63) * BM;
    const int colPanBase = (b >> 6) * 32 + wc * 4;  // first of this wave's B panels

    // --- A prologue: stage full-K A tile via async DMA, single barrier ---
    {
        const int s0 = w * 64 + lane;
        const int s1 = s0 + 256;
        const int r0 = s0 >> 2, p0 = (s0 & 3) ^ ((r0 >> 1) & 3);
        const int r1 = s1 >> 2, p1 = (s1 & 3) ^ ((r1 >> 1) & 3);
        const int go0 = r0 * DIM + p0 * 8;
        const int go1 = r1 * DIM + p1 * 8;
        const int lo0 = (w * 64) * 8;
        const int lo1 = (256 + w * 64) * 8;
        const u16* xb = Xn + (size_t)rowStart * DIM;
        #pragma unroll
        for (int kb = 0; kb < NKB; ++kb) {
            load16(xb + go0 + kb * BK, &As[kb][lo0]);
            load16(xb + go1 + kb * BK, &As[kb][lo1]);
        }
    }

    int aoff[4];
    #pragma unroll
    for (int rg = 0; rg < 4; ++rg)
        aoff[rg] = ((wr * 64 + rg * 16 + lm) * 4 + (lq ^ swz)) * 8;

    // B base pointer (loop-carried across ct; +32768 els = +8 panels).
    const u16* ybase = Ys + (size_t)colPanBase * 4096 + lane * 8;

    floatx4 mn4[4], mx4[4];
    #pragma unroll
    for (int rg = 0; rg < 4; ++rg) {
        mn4[rg] = (floatx4){3.4e38f, 3.4e38f, 3.4e38f, 3.4e38f};
        mx4[rg] = (floatx4){-3.4e38f, -3.4e38f, -3.4e38f, -3.4e38f};
    }

    __syncthreads();  // the ONLY barrier: A tile ready

    short8 P[8], Q[8];
    LOADB64(P, ybase, 0);  // preload ct=0 body 0

    #pragma unroll 1
    for (int ct = 0; ct < NCT; ++ct) {
        const u16* ynext = (ct < NCT - 1) ? (ybase + 32768) : ybase;

        floatx4 acc[4][4];
        #pragma unroll
        for (int i = 0; i < 4; ++i)
            #pragma unroll
            for (int j = 0; j < 4; ++j)
                acc[i][j] = (floatx4){0.0f, 0.0f, 0.0f, 0.0f};

        LOADB64(Q, ybase, 1);   // prefetch body 1
        BODY(P, 0);             // compute body 0
        LOADB64(P, ybase, 2);   // prefetch body 2
        BODY(Q, 1);             // compute body 1
        LOADB64(Q, ybase, 3);   // prefetch body 3
        BODY(P, 2);             // compute body 2
        LOADB64(P, ynext, 0);   // prefetch next ct's body 0
        BODY(Q, 3);             // compute body 3

        // Fold this col-tile into register-carried row min/max.
        #pragma unroll
        for (int rg = 0; rg < 4; ++rg)
            #pragma unroll
            for (int cg = 0; cg < 4; ++cg)
                #pragma unroll
                for (int r = 0; r < 4; ++r) {
                    float m = acc[rg][cg][r];
                    mn4[rg][r] = fminf(mn4[rg][r], m);
                    mx4[rg][r] = fmaxf(mx4[rg][r], m);
                }

        ybase += 32768;  // loop-carried: blocks cross-ct hoisting
    }

    // Single epilogue: quad-lane reduce, eval C twice (quasiconcavity),
    // fire-and-forget atomicMin (no read guard -- R3 post-mortem).
    #pragma unroll
    for (int rg = 0; rg < 4; ++rg) {
        #pragma unroll
        for (int r = 0; r < 4; ++r) {
            float mn = mn4[rg][r];
            float mx = mx4[rg][r];
            #pragma unroll
            for (int mofs = 1; mofs < 16; mofs <<= 1) {
                mn = fminf(mn, __shfl_xor(mn, mofs, 64));
                mx = fmaxf(mx, __shfl_xor(mx, mofs, 64));
            }
            if (lm == 0) {
                float cmin = fminf(c_of_m(mn), c_of_m(mx));
                int row = rowStart + wr * 64 + rg * 16 + lq * 4 + r;
                atomicMinFloat(&out[row], cmin);
            }
        }
    }
}

extern "C" void kernel_launch(void* const* d_in, const int* in_sizes, int n_in,
                              void* d_out, int out_size, void* d_ws, size_t ws_size,
                              hipStream_t stream) {
    const float* Ex = (const float*)d_in[0];
    const float* Ey = (const float*)d_in[1];
    float* out = (float*)d_out;
    u16* Xn = (u16*)d_ws;                // 4 MB, row-major bf16
    u16* Ys = Xn + (size_t)NROWS * DIM;  // 4 MB, B-panel layout bf16

    hipLaunchKernelGGL(normalize_kernel, dim3(NROWS / 4, 2), dim3(256), 0, stream,
                       Ex, Ey, Xn, Ys, out);
    hipLaunchKernelGGL(gemm_min_kernel, dim3(64 * 16), dim3(256), 0, stream,
                       Xn, Ys, out);
}

// Round 11
// 103.630 us; speedup vs baseline: 1.1814x; 1.1814x over previous
//
#include <hip/hip_runtime.h>
#include <hip/hip_bf16.h>

typedef unsigned short u16;
typedef __attribute__((ext_vector_type(8))) short short8;
typedef __attribute__((ext_vector_type(4))) float floatx4;

#define NROWS 8192
#define DIM 256

__device__ __forceinline__ void atomicMinFloat(float* addr, float val) {
    if (val >= 0.0f) {
        atomicMin((int*)addr, __float_as_int(val));
    } else {
        atomicMax((unsigned int*)addr, __float_as_uint(val));
    }
}

__device__ __forceinline__ u16 f32_to_bf16_rne(float x) {
    unsigned int u = __float_as_uint(x);
    unsigned int r = (u + 0x7fffu + ((u >> 16) & 1u)) >> 16;
    return (u16)r;
}

// C(M) = -logp * exp(logp); quasiconcave in M => rowmin = min(C(minM), C(maxM)).
__device__ __forceinline__ float c_of_m(float m) {
    const float INV_SIG = 1.0f / 0.3f;
    const float KC = 0.28503427f;  // -ln(0.3) - 0.5*ln(2*pi)
    float z = (m - 1.0f) * INV_SIG;
    float logp = fmaf(-0.5f * z, z, KC);
    return -logp * __expf(logp);
}

// 16B async DMA global -> LDS. LDS dest is wave-uniform base + lane*16.
__device__ __forceinline__ void load16(const u16* g, u16* l) {
    __builtin_amdgcn_global_load_lds(
        (__attribute__((address_space(1))) void*)g,
        (__attribute__((address_space(3))) void*)l, 16, 0, 0);
}

// Normalize rows (L2-norm clamped at 1e-8), wave per row, float4 loads.
// BOTH X and Y are written in MFMA fragment ("panel") layout:
//   element (row r, k) -> flat[ ((p*8+kt)*64 + lq*16 + lm)*8 + j ]
//   p=r>>4, lm=r&15, kt=k>>5, lq=(k>>3)&3, j=k&7.
// A fragment load (A and B lane maps are identical) is then base + lane*16B:
// one coalesced dwordx4. This data path was verified end-to-end in R5
// (both operands from panels, absmax 1.5e-5).
__global__ __launch_bounds__(256) void normalize_kernel(const float* __restrict__ Ex,
                                                        const float* __restrict__ Ey,
                                                        u16* __restrict__ Xs,
                                                        u16* __restrict__ Ys,
                                                        float* __restrict__ out) {
    const int t = threadIdx.x;
    const int ln = t & 63;
    const int row = blockIdx.x * 4 + (t >> 6);
    const float* src = (blockIdx.y == 0) ? Ex : Ey;
    u16* dst = (blockIdx.y == 0) ? Xs : Ys;

    float4 v = *(const float4*)(src + (size_t)row * DIM + ln * 4);
    float s = fmaf(v.x, v.x, fmaf(v.y, v.y, fmaf(v.z, v.z, v.w * v.w)));
    #pragma unroll
    for (int m = 32; m >= 1; m >>= 1) s += __shfl_xor(s, m, 64);
    float inv = 1.0f / fmaxf(sqrtf(s), 1e-8f);

    ushort4 o;
    o.x = f32_to_bf16_rne(v.x * inv);
    o.y = f32_to_bf16_rne(v.y * inv);
    o.z = f32_to_bf16_rne(v.z * inv);
    o.w = f32_to_bf16_rne(v.w * inv);

    const int p = row >> 4;
    const int lm = row & 15;
    const int kt = ln >> 3;
    const int lq = (ln >> 1) & 3;
    const int j4 = (ln & 1) * 4;
    const size_t off = ((size_t)((p * 8 + kt) * 64 + lq * 16 + lm)) * 8 + j4;
    *(ushort4*)(dst + off) = o;

    if (blockIdx.y == 0 && ln == 0) out[row] = __uint_as_float(0x7f800000u);  // +inf
}

// Block = 128 rows x 512 cols, 4 waves (2x2, wave tile 64x64).
// A: each wave's 64 rows x full K loaded ONCE from panel-layout Xs
//    (L2-resident) into registers a[4][8] (128 VGPRs) -- no A LDS traffic,
//    no A re-reads across col-tiles (R6 spent ~half its LDS-pipe time here).
// B: through LDS with R6's proven DMA mechanics but BK=128 half-K steps
//    (32 KB, double-buffered, 64 KB LDS): only 8 barriers/block, body
//    (~128 MFMAs + 16 KB reads) >> drain, 2 blocks/CU cover the drains.
// Grid: b&63 = row-tile (fixed A per XCD), b>>6 = colgroup (shared B strip).
__global__ void __launch_bounds__(256, 2) __attribute__((amdgpu_waves_per_eu(2, 2)))
gemm_min_kernel(const u16* __restrict__ Xs,
                const u16* __restrict__ Ys,
                float* __restrict__ out) {
    __shared__ u16 Bs[2][32 * 512];  // 2 x 32 KB

    const int tid = threadIdx.x;
    const int w = tid >> 6;
    const int lane = tid & 63;
    const int wr = w >> 1;
    const int wc = w & 1;
    const int lq = lane >> 4;
    const int lm = lane & 15;

    const int b = blockIdx.x;
    const int rowStart = (b & 63) * 128;
    const int rowPan0 = (b & 63) * 8 + wr * 4;
    const u16* ybase = Ys + (size_t)((b >> 6) * 32) * 4096;  // advances 32768/ct

    // --- A into registers, once (32 coalesced dwordx4 per lane) ---
    short8 a[4][8];
    #pragma unroll
    for (int rg = 0; rg < 4; ++rg)
        #pragma unroll
        for (int kt = 0; kt < 8; ++kt)
            a[rg][kt] = *(const short8*)(Xs + ((size_t)(rowPan0 + rg) * 8 + kt) * 512 + lane * 8);

    floatx4 mn4[4], mx4[4];
    #pragma unroll
    for (int rg = 0; rg < 4; ++rg) {
        mn4[rg] = (floatx4){3.4e38f, 3.4e38f, 3.4e38f, 3.4e38f};
        mx4[rg] = (floatx4){-3.4e38f, -3.4e38f, -3.4e38f, -3.4e38f};
    }

    // Stage one 32 KB B half-K chunk (8 panels x 4 kt-units of 1 KB) via DMA.
    // Wave w stages units u = w*8 .. w*8+7; unit u = (panel u>>2, kt u&3).
    auto stageB = [&](int buf, const u16* yb, int h) {
        #pragma unroll
        for (int i = 0; i < 8; ++i) {
            const int u = w * 8 + i;
            load16(yb + (u >> 2) * 4096 + (h * 4 + (u & 3)) * 512 + lane * 8,
                   &Bs[buf][u * 512]);
        }
    };

    stageB(0, ybase, 0);  // prologue: (ct=0, half 0)

    #pragma unroll 1
    for (int ct = 0; ct < 4; ++ct) {
        floatx4 acc[4][4];
        #pragma unroll
        for (int i = 0; i < 4; ++i)
            #pragma unroll
            for (int j = 0; j < 4; ++j)
                acc[i][j] = (floatx4){0.0f, 0.0f, 0.0f, 0.0f};

        // One half-K body: 4 kt x 4 cg B-frag ds_reads (b128, lane-contiguous
        // = conflict-free) x 4 rg MFMAs from the register-resident A array.
        auto compHalf = [&](int buf, int h) {
            #pragma unroll
            for (int kt = 0; kt < 4; ++kt) {
                #pragma unroll
                for (int cg = 0; cg < 4; ++cg) {
                    short8 bf = *(const short8*)(
                        &Bs[buf][(wc * 16 + cg * 4 + kt) * 512 + lane * 8]);
                    #pragma unroll
                    for (int rg = 0; rg < 4; ++rg)
                        acc[rg][cg] = __builtin_amdgcn_mfma_f32_16x16x32_bf16(
                            a[rg][h * 4 + kt], bf, acc[rg][cg], 0, 0, 0);
                }
            }
        };

        __syncthreads();           // drains (ct, h=0) DMA
        stageB(1, ybase, 1);       // prefetch (ct, h=1) into buf 1
        compHalf(0, 0);

        __syncthreads();           // drains (ct, h=1) DMA; all reads of buf0 done
        if (ct < 3)
            stageB(0, ybase + 32768, 0);  // prefetch (ct+1, h=0) into buf 0
        compHalf(1, 1);

        // Fold this col-tile into register-carried row min/max.
        #pragma unroll
        for (int rg = 0; rg < 4; ++rg)
            #pragma unroll
            for (int cg = 0; cg < 4; ++cg)
                #pragma unroll
                for (int r = 0; r < 4; ++r) {
                    float m = acc[rg][cg][r];
                    mn4[rg][r] = fminf(mn4[rg][r], m);
                    mx4[rg][r] = fmaxf(mx4[rg][r], m);
                }

        ybase += 32768;  // loop-carried: blocks cross-ct hoisting
    }

    // Single epilogue: quad-lane reduce, eval C twice (quasiconcavity),
    // fire-and-forget atomicMin (no read guard -- R3 post-mortem).
    #pragma unroll
    for (int rg = 0; rg < 4; ++rg) {
        #pragma unroll
        for (int r = 0; r < 4; ++r) {
            float mn = mn4[rg][r];
            float mx = mx4[rg][r];
            #pragma unroll
            for (int mofs = 1; mofs < 16; mofs <<= 1) {
                mn = fminf(mn, __shfl_xor(mn, mofs, 64));
                mx = fmaxf(mx, __shfl_xor(mx, mofs, 64));
            }
            if (lm == 0) {
                float cmin = fminf(c_of_m(mn), c_of_m(mx));
                int row = rowStart + wr * 64 + rg * 16 + lq * 4 + r;
                atomicMinFloat(&out[row], cmin);
            }
        }
    }
}

extern "C" void kernel_launch(void* const* d_in, const int* in_sizes, int n_in,
                              void* d_out, int out_size, void* d_ws, size_t ws_size,
                              hipStream_t stream) {
    const float* Ex = (const float*)d_in[0];
    const float* Ey = (const float*)d_in[1];
    float* out = (float*)d_out;
    u16* Xs = (u16*)d_ws;                // 4 MB, panel layout
    u16* Ys = Xs + (size_t)NROWS * DIM;  // 4 MB, panel layout

    hipLaunchKernelGGL(normalize_kernel, dim3(NROWS / 4, 2), dim3(256), 0, stream,
                       Ex, Ey, Xs, Ys, out);
    hipLaunchKernelGGL(gemm_min_kernel, dim3(64 * 16), dim3(256), 0, stream,
                       Xs, Ys, out);
}